// Round 23
// baseline (201.325 us; speedup 1.0000x reference)
//
#include <hip/hip_runtime.h>
#include <math.h>

// RecurNN: B=256, L=256, E=100, T=255.
// x_t = W1L*left_t + W1R*right_t + b1; h_t = tanh(x_t); out = sigmoid(W2 h_254 + b2).
// These inputs: right_t always a leaf; left_t = node t-1 (leaf only at t=0).
//
// R23: TWO kernels (kill producer/consumer SIMD interference, R19's residual):
//  phaseA (parallel): c[task] = b1 + [right leaf] W1R*emb  -> d_ws (26MB).
//    1020 blocks x 256 thr (4 waves = k-quarters), 64 tasks/block in 4-task
//    chunks; emb quarter loads ping-pong 2 chunks ahead; partial reduce in LDS.
//    Right-internal tasks (never these inputs) write c = b1; phaseB adds the
//    W1R*hist term. Left-leaf handled by phaseB (it holds W1L).
//  phaseB (sequential): R19 consumer structure, 256 blocks x 256 thr,
//    4 waves = 1 wave/SIMD (NO co-resident producer): wave q owns k-slice
//    [25q,25q+25), lane l rows (l,l+50), 50 weight VGPRs, RL broadcast from
//    own vh; c from d_ws prefetched 2 ticks ahead (ping-pong buckets).
//    One "lgkmcnt(0); s_barrier" per tick; vmcnt never drained.

#define Bc 256
#define Lc 256
#define Ec 100
#define Tc 255
#define W1cols 200

#define RL(v, k) __int_as_float(__builtin_amdgcn_readlane(__float_as_int(v), (k)))
#define RF(x)    __builtin_amdgcn_readfirstlane(x)

#define REP25(X) X(0) X(1) X(2) X(3) X(4) X(5) X(6) X(7) X(8) X(9) X(10) X(11) X(12) \
                 X(13) X(14) X(15) X(16) X(17) X(18) X(19) X(20) X(21) X(22) X(23) X(24)
#define DECLW(j) float wA##j, wB##j;
#define CM2(a,b) { const float ra_ = RL(sv,(a)), rb_ = RL(sv,(b)); \
    accA0 = fmaf(ra_, wA##a, accA0); accB0 = fmaf(ra_, wB##a, accB0); \
    accA1 = fmaf(rb_, wA##b, accA1); accB1 = fmaf(rb_, wB##b, accB1); }
#define CM1(a) { const float ra_ = RL(sv,(a)); \
    accA0 = fmaf(ra_, wA##a, accA0); accB0 = fmaf(ra_, wB##a, accB0); }
#define CMALL CM2(0,1) CM2(2,3) CM2(4,5) CM2(6,7) CM2(8,9) CM2(10,11) CM2(12,13) \
              CM2(14,15) CM2(16,17) CM2(18,19) CM2(20,21) CM2(22,23) CM1(24)

#define BARRIER asm volatile("s_waitcnt lgkmcnt(0)\n\ts_barrier" ::: "memory");

// generic right-internal fallback (global weights; never hot for these inputs)
__device__ __noinline__ float slow_dot(const float* rp, const float* wr) {
    float a0 = 0.f, a1 = 0.f, a2 = 0.f, a3 = 0.f;
    for (int qq = 0; qq < 25; ++qq) {
        float4 h4 = *(const float4*)(rp + 4 * qq);
        float4 w4 = *(const float4*)(wr + 4 * qq);
        a0 = fmaf(w4.x, h4.x, a0); a1 = fmaf(w4.y, h4.y, a1);
        a2 = fmaf(w4.z, h4.z, a2); a3 = fmaf(w4.w, h4.w, a3);
    }
    return (a0 + a1) + (a2 + a3);
}

// ============================== phaseA ==============================
__global__ __launch_bounds__(256, 2)
void phaseA(const int* __restrict__ token_ids,
            const int* __restrict__ comp_right,
            const float* __restrict__ emb,
            const float* __restrict__ W1,
            const float* __restrict__ b1,
            float* __restrict__ c_ws)
{
    const int tid = threadIdx.x;
    const int q   = tid >> 6;               // wave = k-quarter
    const int l   = tid & 63;
    const int lc  = (l < 50) ? l : 49;
    const int base = blockIdx.x * 64;       // 64 tasks per block

    __shared__ float part[4][4][Ec];        // [task-in-chunk][q][row]
    __shared__ int   tokS[64];

    if (tid < 64) {
        const int task = base + tid;
        const int cr = comp_right[task];
        const int bq = task / Tc;
        tokS[tid] = (cr < Lc) ? token_ids[bq * Lc + cr] : -1;
    }

    // W1R rows (lc, lc+50), k-quarter q -> 50 named scalars
    const float* prowA = W1 + (size_t)lc * W1cols + Ec + 25 * q;
    const float* prowB = W1 + (size_t)(lc + 50) * W1cols + Ec + 25 * q;
    REP25(DECLW)
#define LOADW(j) { wA##j = prowA[j]; wB##j = prowB[j]; }
    REP25(LOADW)
#undef LOADW
    const float b1j   = b1[lc];
    const float b1j50 = b1[lc + 50];

    __syncthreads();                        // tokS visible

#define PLOAD(dst, tkd, s) { tkd = tokS[(s)]; dst = 0.f; \
    if (tkd >= 0 && l < 25) dst = emb[(size_t)tkd * Ec + 25 * q + l]; }
#define PTASK(sv_, tk_, slot) { \
    float accA0 = 0.f, accA1 = 0.f, accB0 = 0.f, accB1 = 0.f; \
    if (tk_ >= 0) { const float sv = sv_; CMALL } \
    if (l < 50) { part[slot][q][lc]      = accA0 + accA1; \
                  part[slot][q][lc + 50] = accB0 + accB1; } }
#define FINAL(ch) { const int task = base + (ch) * 4 + q; \
    if (l < 50) { \
        float x0 = ((part[q][0][l] + part[q][1][l]) + \
                    (part[q][2][l] + part[q][3][l])) + b1j; \
        float x1 = ((part[q][0][l + 50] + part[q][1][l + 50]) + \
                    (part[q][2][l + 50] + part[q][3][l + 50])) + b1j50; \
        c_ws[(size_t)task * Ec + l]      = x0; \
        c_ws[(size_t)task * Ec + 50 + l] = x1; } }

    // prologue: load chunks 0 (set A) and 1 (set B)
    float eA0, eA1, eA2, eA3, eB0, eB1, eB2, eB3;
    int   tA0, tA1, tA2, tA3, tB0, tB1, tB2, tB3;
    PLOAD(eA0, tA0, 0) PLOAD(eA1, tA1, 1) PLOAD(eA2, tA2, 2) PLOAD(eA3, tA3, 3)
    PLOAD(eB0, tB0, 4) PLOAD(eB1, tB1, 5) PLOAD(eB2, tB2, 6) PLOAD(eB3, tB3, 7)

    #pragma unroll 1
    for (int k = 0; k < 8; ++k) {           // chunk pair (2k, 2k+1)
        // ---- chunk 2k (set A) ----
        PTASK(eA0, tA0, 0) PTASK(eA1, tA1, 1) PTASK(eA2, tA2, 2) PTASK(eA3, tA3, 3)
        if (k < 7) {                        // reload A for chunk 2k+2
            const int s0 = (2 * k + 2) * 4;
            PLOAD(eA0, tA0, s0) PLOAD(eA1, tA1, s0 + 1)
            PLOAD(eA2, tA2, s0 + 2) PLOAD(eA3, tA3, s0 + 3)
        }
        BARRIER
        FINAL(2 * k)
        BARRIER
        // ---- chunk 2k+1 (set B) ----
        PTASK(eB0, tB0, 0) PTASK(eB1, tB1, 1) PTASK(eB2, tB2, 2) PTASK(eB3, tB3, 3)
        if (k < 7) {                        // reload B for chunk 2k+3
            const int s0 = (2 * k + 3) * 4;
            PLOAD(eB0, tB0, s0) PLOAD(eB1, tB1, s0 + 1)
            PLOAD(eB2, tB2, s0 + 2) PLOAD(eB3, tB3, s0 + 3)
        }
        BARRIER
        FINAL(2 * k + 1)
        BARRIER
    }
#undef PLOAD
#undef PTASK
#undef FINAL
}

// ============================== phaseB ==============================
__global__ __launch_bounds__(256, 1)
void phaseB(const int* __restrict__ token_ids,
            const int* __restrict__ comp_left,
            const int* __restrict__ comp_right,
            const float* __restrict__ emb,
            const float* __restrict__ W1,
            const float* __restrict__ W2,
            const float* __restrict__ b2,
            const float* __restrict__ c_ws,
            float* __restrict__ out)
{
    const int b   = blockIdx.x;
    const int tid = threadIdx.x;           // 0..255, 4 waves (1/SIMD)
    const int q   = tid >> 6;              // k-slice
    const int l   = tid & 63;
    const int lc  = (l < 50) ? l : 49;

    __shared__ __align__(16) float hist[Tc * Ec];   // generic paths only
    __shared__ float part[2][4][Ec];                // ping-pong partials
    __shared__ int2  ccS[Tc];
    __shared__ int   tokLS[Tc];
    __shared__ float red[4];

    for (int i = tid; i < Tc; i += 256) {
        const int cl = comp_left [b * Tc + i];
        ccS[i]   = make_int2(cl, comp_right[b * Tc + i]);
        tokLS[i] = (cl < Lc) ? token_ids[b * Lc + cl] : -1;
    }

    // W1L rows (lc, lc+50), k-slice q -> 50 named scalars
    const float* prowA = W1 + (size_t)lc * W1cols + 25 * q;
    const float* prowB = W1 + (size_t)(lc + 50) * W1cols + 25 * q;
    REP25(DECLW)
#define LOADW(j) { wA##j = prowA[j]; wB##j = prowB[j]; }
    REP25(LOADW)
#undef LOADW

    const float* cb = c_ws + (size_t)b * Tc * Ec;

    __syncthreads();

    // ---- state ----
    float vh = 0.f;                        // lane j<25: h[25q+j]
    int2  cc = ccS[0];
    float cB0 = 0.f, cB1 = 0.f;            // c buckets (tc even / odd)
    if (l < 25) {
        cB0 = cb[0 * Ec + 25 * q + l];     // tc=0
        cB1 = cb[1 * Ec + 25 * q + l];     // tc=1
    }

// one tick: I runtime, PPc compile-time ping-pong, CB = bucket reg (tc&1)
#define TICK(I, PPc, CB)                                                      \
{                                                                             \
    const int i_ = (I);                                                       \
    const int tc = i_ - 1;                                                    \
    if (tc >= 0) {                                                            \
        __builtin_amdgcn_s_setprio(1);                                        \
        const int li = RF(cc.x);                                              \
        const int ri = RF(cc.y);                                              \
        float sv = 0.f;                                                       \
        if (tc >= 1 && li == Lc + tc - 1) {                                   \
            sv = vh;                           /* register fast path */       \
        } else if (li >= Lc) {                                                \
            const int n = li - Lc;                                            \
            if (n < tc && l < 25) sv = hist[n * Ec + 25 * q + l];             \
        } else {                               /* left leaf (t==0) */         \
            const int tl = RF(tokLS[tc]);                                     \
            if (tl >= 0 && l < 25) sv = emb[(size_t)tl * Ec + 25 * q + l];    \
        }                                                                     \
        float accA0 = 0.f, accA1 = 0.f, accB0 = 0.f, accB1 = 0.f;             \
        CMALL                                                                 \
        if (l < 50) {                                                         \
            part[PPc][q][lc]      = accA0 + accA1;                            \
            part[PPc][q][lc + 50] = accB0 + accB1;                            \
        }                                                                     \
        BARRIER                                                               \
        if (l < 25) {                                                         \
            const int r = 25 * q + l;                                         \
            float x = ((part[PPc][0][r] + part[PPc][1][r]) +                  \
                       (part[PPc][2][r] + part[PPc][3][r])) + CB;             \
            if (ri >= Lc) {                    /* generic right-internal */   \
                const int n2 = ri - Lc;                                       \
                if (n2 < tc) x += slow_dot(&hist[n2 * Ec],                    \
                                           W1 + (size_t)r * W1cols + Ec);     \
            }                                                                 \
            const float u = __expf(2.f * x);                                  \
            vh = 1.f - 2.f / (u + 1.f);        /* tanh, exact identity */     \
            hist[tc * Ec + r] = vh;            /* generic paths only */       \
        }                                                                     \
        /* bucket consumed; reload for tc+2 (2-tick flight, L2/L3 c_ws) */    \
        {                                                                     \
            const int t2 = tc + 2;                                            \
            float nv = 0.f;                                                   \
            if (t2 < Tc && l < 25) nv = cb[(size_t)t2 * Ec + 25 * q + l];     \
            CB = nv;                                                          \
        }                                                                     \
        __builtin_amdgcn_s_setprio(0);                                        \
        if (tc + 1 < Tc) cc = ccS[tc + 1];                                    \
    } else {                                                                  \
        BARRIER                                                               \
    }                                                                         \
}

    // ---- main loop: ticks 0..255 (tc 0..254), unroll-2 ----
    // tc parity: i2 even tick -> tc odd -> bucket cB1; odd tick -> cB0.
    #pragma unroll 1
    for (int i2 = 0; i2 < 256; i2 += 2) {
        TICK(i2,     1, cB1)
        TICK(i2 + 1, 0, cB0)
    }
#undef TICK

    // ---- out[b] = sigmoid(W2 . h_254 + b2) ----
    {
        float pv = 0.f;
        if (l < 25) pv = W2[25 * q + l] * vh;
        #pragma unroll
        for (int off = 32; off > 0; off >>= 1) pv += __shfl_down(pv, off, 64);
        if (l == 0) red[q] = pv;
    }
    __syncthreads();
    if (tid == 0)
        out[b] = 1.f / (1.f + __expf(-((red[0] + red[1]) + (red[2] + red[3]) + b2[0])));
}

extern "C" void kernel_launch(void* const* d_in, const int* in_sizes, int n_in,
                              void* d_out, int out_size, void* d_ws, size_t ws_size,
                              hipStream_t stream) {
    const int*   token_ids  = (const int*)  d_in[0];
    const int*   comp_left  = (const int*)  d_in[1];
    const int*   comp_right = (const int*)  d_in[2];
    const float* emb        = (const float*)d_in[3];
    const float* W1         = (const float*)d_in[4];
    const float* b1         = (const float*)d_in[5];
    const float* W2         = (const float*)d_in[6];
    const float* b2         = (const float*)d_in[7];
    float*       out        = (float*)d_out;
    float*       c_ws       = (float*)d_ws;   // B*T*E*4 = 26,112,000 B <= ws_size

    phaseA<<<(Bc * Tc) / 64, 256, 0, stream>>>(token_ids, comp_right,
                                               emb, W1, b1, c_ws);
    phaseB<<<Bc, 256, 0, stream>>>(token_ids, comp_left, comp_right,
                                   emb, W1, W2, b2, c_ws, out);
}